// Round 1
// baseline (156.473 us; speedup 1.0000x reference)
//
#include <hip/hip_runtime.h>

typedef __attribute__((ext_vector_type(8))) short short8;
typedef __attribute__((ext_vector_type(4))) float f32x4;
typedef unsigned short u16;

#define Bn 8
#define Tn 2048
#define Cn 1024
#define Hn 64
#define Mrows (Bn * Tn)  // 16384

__device__ __forceinline__ u16 f2bf(float f) {
    union { float f; unsigned u; } c; c.f = f;
    unsigned u = c.u;
    unsigned r = (u + 0x7fffu + ((u >> 16) & 1u)) >> 16;
    return (u16)r;
}

// W [1024][64] f32 -> wt [64][1024] bf16 (transposed), with scale folded in.
__global__ void convert_w(const float* __restrict__ W, u16* __restrict__ wt, float scale) {
    int idx = blockIdx.x * 256 + threadIdx.x;  // 0..65535
    int k = idx >> 6, n = idx & 63;
    wt[n * Cn + k] = f2bf(W[idx] * scale);
}

// x [16384][1024] f32 @ wt^T -> qkv bf16, 3 matrices of [16384][64].
// Block: 64 rows x 192 cols, 8 waves (4M x 2N), BK=64.
__global__ __launch_bounds__(512) void qkv_proj(const float* __restrict__ x,
                                                const u16* __restrict__ wt,
                                                u16* __restrict__ qkv) {
    __shared__ u16 xs[64][72];  // +8 pad: 2-way bank conflict only (free)
    const int tid = threadIdx.x;
    const int lane = tid & 63;
    const int wid = tid >> 6;
    const int wm = wid >> 1;  // 0..3 -> 16-row slice
    const int wn = wid & 1;   // 0..1 -> 96-col slice
    const int row0 = blockIdx.x * 64;
    const int l15 = lane & 15;
    const int lhi = lane >> 4;
    const int trow = tid >> 3;
    const int tk8 = (tid & 7) * 8;

    f32x4 acc[6];
    for (int j = 0; j < 6; ++j) acc[j] = f32x4{0.f, 0.f, 0.f, 0.f};

    for (int ko = 0; ko < Cn; ko += 64) {
        __syncthreads();
        // stage x tile [64][64] f32 -> bf16 LDS
        const float* src = x + (size_t)(row0 + trow) * Cn + ko + tk8;
        f32x4 a0 = *(const f32x4*)(src);
        f32x4 a1 = *(const f32x4*)(src + 4);
        short8 pack;
        pack[0] = (short)f2bf(a0[0]); pack[1] = (short)f2bf(a0[1]);
        pack[2] = (short)f2bf(a0[2]); pack[3] = (short)f2bf(a0[3]);
        pack[4] = (short)f2bf(a1[0]); pack[5] = (short)f2bf(a1[1]);
        pack[6] = (short)f2bf(a1[2]); pack[7] = (short)f2bf(a1[3]);
        *(short8*)&xs[trow][tk8] = pack;
        __syncthreads();

        for (int kc = 0; kc < 2; ++kc) {
            short8 af = *(const short8*)&xs[wm * 16 + l15][kc * 32 + lhi * 8];
            for (int nj = 0; nj < 6; ++nj) {
                int gcol = wn * 96 + nj * 16 + l15;
                short8 bf = *(const short8*)(wt + (size_t)gcol * Cn + ko + kc * 32 + lhi * 8);
                acc[nj] = __builtin_amdgcn_mfma_f32_16x16x32_bf16(af, bf, acc[nj], 0, 0, 0);
            }
        }
    }
    for (int nj = 0; nj < 6; ++nj) {
        int gcolb = wn * 96 + nj * 16 + l15;
        int mat = gcolb >> 6, lcol = gcolb & 63;
        u16* dst = qkv + (size_t)mat * (Mrows * Hn);
        for (int r = 0; r < 4; ++r) {
            int grow = row0 + wm * 16 + lhi * 4 + r;
            dst[(size_t)grow * Hn + lcol] = f2bf(acc[nj][r]);
        }
    }
}

// Flash attention, causal. One wave per 16 q-rows. k-tiles of 64.
// Scale (C^-0.5 * log2e) is folded into q, so softmax uses exp2f.
__global__ __launch_bounds__(64) void attn_fwd(const u16* __restrict__ q,
                                               const u16* __restrict__ k,
                                               const u16* __restrict__ v,
                                               float* __restrict__ out) {
    __shared__ u16 pl[16][72];
    const int lane = threadIdx.x;
    const int l15 = lane & 15, lhi = lane >> 4;
    const int b = blockIdx.y;
    const int qt = (int)(gridDim.x - 1) - (int)blockIdx.x;  // longest blocks first
    const int q0 = qt * 16;
    const u16* qb = q + (size_t)b * Tn * Hn;
    const u16* kbp = k + (size_t)b * Tn * Hn;
    const u16* vb = v + (size_t)b * Tn * Hn;

    short8 qf[2];
    for (int kc = 0; kc < 2; ++kc)
        qf[kc] = *(const short8*)(qb + (size_t)(q0 + l15) * Hn + kc * 32 + lhi * 8);

    float m[4], ssum[4];
    f32x4 o[4];
    for (int r = 0; r < 4; ++r) { m[r] = -1e30f; ssum[r] = 0.f; }
    for (int dt = 0; dt < 4; ++dt) o[dt] = f32x4{0.f, 0.f, 0.f, 0.f};

    const int nkt = (q0 >> 6) + 1;
    for (int kbi = 0; kbi < nkt; ++kbi) {
        const int k0 = kbi * 64;
        f32x4 sacc[4];
        for (int kt = 0; kt < 4; ++kt) sacc[kt] = f32x4{0.f, 0.f, 0.f, 0.f};
        for (int kc = 0; kc < 2; ++kc) {
            for (int kt = 0; kt < 4; ++kt) {
                short8 kf = *(const short8*)(kbp + (size_t)(k0 + kt * 16 + l15) * Hn + kc * 32 + lhi * 8);
                sacc[kt] = __builtin_amdgcn_mfma_f32_16x16x32_bf16(qf[kc], kf, sacc[kt], 0, 0, 0);
            }
        }
        if (kbi == nkt - 1) {  // diagonal tile: causal mask
            for (int kt = 0; kt < 4; ++kt)
                for (int r = 0; r < 4; ++r) {
                    int kg = k0 + kt * 16 + l15;
                    int qg = q0 + lhi * 4 + r;
                    if (kg > qg) sacc[kt][r] = -1e30f;
                }
        }
        // online softmax (per q-row r; row spread across 16 lanes of same lhi group)
        for (int r = 0; r < 4; ++r) {
            float tmax = fmaxf(fmaxf(sacc[0][r], sacc[1][r]), fmaxf(sacc[2][r], sacc[3][r]));
            tmax = fmaxf(tmax, __shfl_xor(tmax, 1));
            tmax = fmaxf(tmax, __shfl_xor(tmax, 2));
            tmax = fmaxf(tmax, __shfl_xor(tmax, 4));
            tmax = fmaxf(tmax, __shfl_xor(tmax, 8));
            float mnew = fmaxf(m[r], tmax);
            float corr = exp2f(m[r] - mnew);
            float psum = 0.f;
            for (int kt = 0; kt < 4; ++kt) {
                float p = exp2f(sacc[kt][r] - mnew);
                sacc[kt][r] = p;
                psum += p;
            }
            psum += __shfl_xor(psum, 1);
            psum += __shfl_xor(psum, 2);
            psum += __shfl_xor(psum, 4);
            psum += __shfl_xor(psum, 8);
            ssum[r] = ssum[r] * corr + psum;
            m[r] = mnew;
            for (int dt = 0; dt < 4; ++dt) o[dt][r] *= corr;
        }
        // P (D-layout) -> LDS -> A-fragment layout. Wave-private: no barrier.
        for (int kt = 0; kt < 4; ++kt)
            for (int r = 0; r < 4; ++r)
                pl[lhi * 4 + r][kt * 16 + l15] = f2bf(sacc[kt][r]);
        short8 pf[2];
        for (int kc = 0; kc < 2; ++kc)
            pf[kc] = *(const short8*)&pl[l15][kc * 32 + lhi * 8];
        // PV
        for (int dt = 0; dt < 4; ++dt) {
            for (int kc = 0; kc < 2; ++kc) {
                short8 vf;
                for (int e = 0; e < 8; ++e)
                    vf[e] = (short)vb[(size_t)(k0 + kc * 32 + lhi * 8 + e) * Hn + dt * 16 + l15];
                o[dt] = __builtin_amdgcn_mfma_f32_16x16x32_bf16(pf[kc], vf, o[dt], 0, 0, 0);
            }
        }
    }
    float* ob = out + (size_t)b * Tn * Hn;
    for (int dt = 0; dt < 4; ++dt)
        for (int r = 0; r < 4; ++r)
            ob[(size_t)(q0 + lhi * 4 + r) * Hn + dt * 16 + l15] = o[dt][r] / ssum[r];
}

extern "C" void kernel_launch(void* const* d_in, const int* in_sizes, int n_in,
                              void* d_out, int out_size, void* d_ws, size_t ws_size,
                              hipStream_t stream) {
    const float* x = (const float*)d_in[0];
    const float* Wq = (const float*)d_in[1];
    const float* Wk = (const float*)d_in[2];
    const float* Wv = (const float*)d_in[3];
    float* out = (float*)d_out;
    char* ws = (char*)d_ws;

    u16* wt = (u16*)ws;                              // [192][1024] bf16
    u16* qkv = (u16*)(ws + 192 * Cn * 2);            // 3 x [16384][64] bf16

    // fold C^-0.5 * log2(e) into Wq so attention uses exp2
    const float qscale = 0.04508422002778011f;
    convert_w<<<256, 256, 0, stream>>>(Wq, wt + 0 * Hn * Cn, qscale);
    convert_w<<<256, 256, 0, stream>>>(Wk, wt + 1 * Hn * Cn, 1.0f);
    convert_w<<<256, 256, 0, stream>>>(Wv, wt + 2 * Hn * Cn, 1.0f);

    qkv_proj<<<256, 512, 0, stream>>>(x, wt, qkv);

    attn_fwd<<<dim3(Tn / 16, Bn), 64, 0, stream>>>(
        qkv, qkv + (size_t)Mrows * Hn, qkv + 2 * (size_t)Mrows * Hn, out);
}